// Round 16
// baseline (499.853 us; speedup 1.0000x reference)
//
#include <hip/hip_runtime.h>
#include <stdint.h>
#include <stddef.h>

#define FIN 512
#define FOUT 128
#define BROWS 160      // rows per bucket -> NB = 625
#define NBK 625
#define SORT_CAP 7680  // LDS-staged records per bucket (mean 5120, sigma ~72)
#define TILE 8192      // edges per tilesort block
#define MAXNT 512      // fragment descriptor capacity (NT = 391)
#define NCH 8          // feature chunks (16 feats each); chunk -> XCD plane
#define PTILE 128      // rows per plane-tile in rowp_k
#define PSTCAP 5120    // staged records per plane-tile (mean 4096, +16 sigma)

typedef __attribute__((ext_vector_type(8))) short short8;
typedef __attribute__((ext_vector_type(4))) float f32x4;

__device__ __forceinline__ unsigned short f2bf(float f) {
  unsigned u = __builtin_bit_cast(unsigned, f);
  u = (u + 0x7fffu + ((u >> 16) & 1u)) >> 16;
  return (unsigned short)u;
}
__device__ __forceinline__ float bf2f(unsigned short h) {
  unsigned u = ((unsigned)h) << 16;
  return __builtin_bit_cast(float, u);
}

// theta [512][128] f32 -> thetaT [128][512] bf16
__global__ void prep_theta_k(const float* __restrict__ theta,
                             unsigned short* __restrict__ thetaT) {
  int idx = blockIdx.x * blockDim.x + threadIdx.x;  // 65536
  int n = idx >> 9;
  int k = idx & 511;
  thetaT[idx] = f2bf(theta[k * FOUT + n]);
}

// ybc[chunk][node][16] bf16 = x[M][512] f32 @ thetaT^T, 16x16x32 MFMA.
__global__ __launch_bounds__(256) void gemm_k(const float* __restrict__ x,
                                              const unsigned short* __restrict__ thetaT,
                                              unsigned short* __restrict__ ybc, int M) {
  __shared__ __align__(16) unsigned short lA[128 * 40];
  __shared__ __align__(16) unsigned short lB[128 * 40];
  const int tid = threadIdx.x;
  const int row0 = blockIdx.x * 128;
  const int wave = tid >> 6, lane = tid & 63;
  const int wm = wave >> 1, wn = wave & 1;
  const int fr = lane & 15, fq = lane >> 4;
  const int arow = tid >> 1, ahalf = tid & 1;

  f32x4 acc[4][4] = {};

  const int grow = row0 + arow;
  const bool aval = (grow < M);
  const float* asrc = x + (size_t)(aval ? grow : 0) * FIN + ahalf * 16;
  const unsigned short* bsrc = thetaT + (size_t)arow * FIN + ahalf * 16;

  for (int k0 = 0; k0 < FIN; k0 += 32) {
    float av[16];
    if (aval) {
      const float4* p = (const float4*)(asrc + k0);
      float4 v0 = p[0], v1 = p[1], v2 = p[2], v3 = p[3];
      av[0] = v0.x; av[1] = v0.y; av[2] = v0.z; av[3] = v0.w;
      av[4] = v1.x; av[5] = v1.y; av[6] = v1.z; av[7] = v1.w;
      av[8] = v2.x; av[9] = v2.y; av[10] = v2.z; av[11] = v2.w;
      av[12] = v3.x; av[13] = v3.y; av[14] = v3.z; av[15] = v3.w;
    } else {
      for (int i = 0; i < 16; i++) av[i] = 0.f;
    }
    unsigned ap[8];
    for (int i = 0; i < 8; i++)
      ap[i] = (unsigned)f2bf(av[2 * i]) | ((unsigned)f2bf(av[2 * i + 1]) << 16);
    uint4* aw = (uint4*)&lA[arow * 40 + ahalf * 16];
    aw[0] = make_uint4(ap[0], ap[1], ap[2], ap[3]);
    aw[1] = make_uint4(ap[4], ap[5], ap[6], ap[7]);

    const uint4* bp = (const uint4*)(bsrc + k0);
    uint4 b0 = bp[0], b1 = bp[1];
    uint4* bw = (uint4*)&lB[arow * 40 + ahalf * 16];
    bw[0] = b0; bw[1] = b1;

    __syncthreads();

    short8 af[4], bfv[4];
#pragma unroll
    for (int m = 0; m < 4; m++)
      af[m] = *(const short8*)&lA[(wm * 64 + m * 16 + fr) * 40 + fq * 8];
#pragma unroll
    for (int n = 0; n < 4; n++)
      bfv[n] = *(const short8*)&lB[(wn * 64 + n * 16 + fr) * 40 + fq * 8];
#pragma unroll
    for (int m = 0; m < 4; m++)
#pragma unroll
      for (int n = 0; n < 4; n++)
        acc[m][n] = __builtin_amdgcn_mfma_f32_16x16x32_bf16(af[m], bfv[n], acc[m][n], 0, 0, 0);

    __syncthreads();
  }

  // C/D: col = lane&15 (=fr), row = fq*4 + j; chunk = wn*4 + n
#pragma unroll
  for (int m = 0; m < 4; m++) {
    int rbase = row0 + wm * 64 + m * 16 + fq * 4;
#pragma unroll
    for (int j = 0; j < 4; j++) {
      int r = rbase + j;
      if (r < M) {
#pragma unroll
        for (int n = 0; n < 4; n++) {
          int c = wn * 4 + n;
          ybc[((size_t)c * M + r) * 16 + fr] = f2bf(acc[m][n][j]);
        }
      }
    }
  }
}

// tilesort: per 8192-edge tile, LDS count-sort by bucket, dump contiguous.
// Also accumulates per-bucket global totals.
__global__ __launch_bounds__(256) void tilesort_k(const int* __restrict__ rows,
                                                  const int* __restrict__ cols,
                                                  const float* __restrict__ vals,
                                                  unsigned* __restrict__ rec4tile,
                                                  unsigned char* __restrict__ rlotile,
                                                  int* __restrict__ lofs,
                                                  int* __restrict__ btotals, int E) {
  __shared__ int hist[NBK];
  __shared__ int wsum[4];
  __shared__ unsigned srec[TILE];
  __shared__ unsigned char srlo[TILE];
  const int c = blockIdx.x, t = threadIdx.x;
  const int base = c * TILE;
  const int n = (E - base < TILE) ? (E - base) : TILE;

  for (int i = t; i < NBK; i += 256) hist[i] = 0;
  __syncthreads();

#pragma unroll
  for (int k = 0; k < TILE / 256; k++) {
    int i = base + k * 256 + t;
    if (i < E) atomicAdd(&hist[rows[i] / BROWS], 1);
  }
  __syncthreads();

  int c0 = t * 3, c1 = c0 + 1, c2 = c0 + 2;
  int h0 = (c0 < NBK) ? hist[c0] : 0;
  int h1 = (c1 < NBK) ? hist[c1] : 0;
  int h2 = (c2 < NBK) ? hist[c2] : 0;
  if (h0) atomicAdd(&btotals[c0], h0);
  if (h1) atomicAdd(&btotals[c1], h1);
  if (h2) atomicAdd(&btotals[c2], h2);
  int loc = h0 + h1 + h2;
  int lane = t & 63, wv = t >> 6;
  int inc = loc;
  for (int off = 1; off < 64; off <<= 1) {
    int u = __shfl_up(inc, off, 64);
    if (lane >= off) inc += u;
  }
  if (lane == 63) wsum[wv] = inc;
  __syncthreads();
  int excl = inc - loc;
  for (int i = 0; i < 4; i++)
    if (i < wv) excl += wsum[i];

  size_t lbase = (size_t)c * (NBK + 1);
  int e = excl;
  if (c0 <= NBK) lofs[lbase + c0] = e;
  __syncthreads();
  if (c0 < NBK) hist[c0] = e;
  e += h0;
  if (c1 <= NBK) lofs[lbase + c1] = e;
  if (c1 < NBK) hist[c1] = e;
  e += h1;
  if (c2 <= NBK) lofs[lbase + c2] = e;
  if (c2 < NBK) hist[c2] = e;
  __syncthreads();

#pragma unroll
  for (int k = 0; k < TILE / 256; k++) {
    int i = base + k * 256 + t;
    if (i < E) {
      int r = rows[i];
      int b = r / BROWS;
      int p = atomicAdd(&hist[b], 1);
      srec[p] = ((unsigned)cols[i] << 15) | ((unsigned)f2bf(vals[i]) & 0x7fffu);
      srlo[p] = (unsigned char)(r - b * BROWS);
    }
  }
  __syncthreads();

  for (int j = t; j < n; j += 256) {
    rec4tile[base + j] = srec[j];
    rlotile[base + j] = srlo[j];
  }
}

// single-block exclusive scan of 625 bucket totals -> boff; sentinels; q init
__global__ __launch_bounds__(1024) void bscan_k(const int* __restrict__ btotals,
                                                int* __restrict__ boff,
                                                int* __restrict__ offsets,
                                                int* __restrict__ q,
                                                int E, int M) {
  __shared__ int tmp[1024];
  int t = threadIdx.x;
  tmp[t] = (t < NBK) ? btotals[t] : 0;
  __syncthreads();
  for (int off = 1; off < 1024; off <<= 1) {
    int v = (t >= off) ? tmp[t - off] : 0;
    __syncthreads();
    tmp[t] += v;
    __syncthreads();
  }
  if (t < NBK) boff[t] = t ? tmp[t - 1] : 0;
  if (t < NCH) q[t] = 0;
  if (t == 0) {
    boff[NBK] = E;
    offsets[M] = E;
  }
}

// per-bucket: coalesced fragment gather, LDS count-sort by rlo, write sorted.
__global__ __launch_bounds__(256) void bsort_k(const int* __restrict__ boff,
                                               const int* __restrict__ lofs,
                                               const unsigned* __restrict__ rec4tile,
                                               const unsigned char* __restrict__ rlotile,
                                               unsigned* __restrict__ rec4s,
                                               int* __restrict__ offsets,
                                               int NT, int M) {
  __shared__ unsigned s4[SORT_CAP];
  __shared__ unsigned char k8[SORT_CAP];
  __shared__ int lh[256];
  __shared__ int lsc[256];
  __shared__ int wsum[4];
  __shared__ int fsrc[MAXNT];
  __shared__ int fdst[MAXNT];
  __shared__ int flen[MAXNT];
  int b = blockIdx.x, t = threadIdx.x;
  int start = boff[b];

  int ca = 2 * t, cb = 2 * t + 1;
  int la = 0, fa = 0, lb2 = 0, fb = 0;
  if (ca < NT) {
    size_t p = (size_t)ca * (NBK + 1) + b;
    la = lofs[p];
    fa = lofs[p + 1] - la;
  }
  if (cb < NT) {
    size_t p = (size_t)cb * (NBK + 1) + b;
    lb2 = lofs[p];
    fb = lofs[p + 1] - lb2;
  }
  int loc = fa + fb;
  int lane = t & 63, wv = t >> 6;
  int inc = loc;
  for (int off = 1; off < 64; off <<= 1) {
    int u = __shfl_up(inc, off, 64);
    if (lane >= off) inc += u;
  }
  if (lane == 63) wsum[wv] = inc;
  __syncthreads();
  int excl = inc - loc;
  for (int i = 0; i < 4; i++)
    if (i < wv) excl += wsum[i];

  if (ca < NT) {
    fsrc[ca] = ca * TILE + la;
    fdst[ca] = excl;
    flen[ca] = fa;
  }
  if (cb < NT) {
    fsrc[cb] = cb * TILE + lb2;
    fdst[cb] = excl + fa;
    flen[cb] = fb;
  }
  lh[t] = 0;
  __syncthreads();

  int grp = t >> 4, l16 = t & 15;
  for (int f = grp; f < NT; f += 16) {
    int L = flen[f];
    int sd = fdst[f];
    int ss = fsrc[f];
    for (int j = l16; j < L; j += 16) {
      int d = sd + j;
      if (d < SORT_CAP) {
        s4[d] = rec4tile[ss + j];
        k8[d] = rlotile[ss + j];
      }
    }
  }

  int n = boff[b + 1] - start;
  if (n > SORT_CAP) n = SORT_CAP;
  __syncthreads();

  for (int i = t; i < n; i += 256) atomicAdd(&lh[k8[i]], 1);
  __syncthreads();
  lsc[t] = lh[t];
  __syncthreads();
  for (int off = 1; off < 256; off <<= 1) {
    int v = (t >= off) ? lsc[t - off] : 0;
    __syncthreads();
    lsc[t] += v;
    __syncthreads();
  }
  int ex = t ? lsc[t - 1] : 0;
  int row = b * BROWS + t;
  if (t < BROWS && row < M) offsets[row] = start + ex;
  lh[t] = ex;
  __syncthreads();
  for (int i = t; i < n; i += 256) {
    unsigned r = s4[i];
    int p = atomicAdd(&lh[k8[i]], 1);
    rec4s[start + p] = r;
  }
}

// XCD-affine row phase: 8 passes over 16-feat planes (3.2MB, fits own L2).
// Per block-tile (128 rows): stage rec4 via NT into LDS (touched once/pass),
// then 2 lanes/row x uint4 gather from the resident plane, unroll x2, NT out.
__global__ __launch_bounds__(256) void rowp_k(const int* __restrict__ offsets,
                                              const unsigned* __restrict__ rec4,
                                              const unsigned short* __restrict__ ybc,
                                              const float* __restrict__ bias,
                                              float* __restrict__ out,
                                              int* __restrict__ q, int M) {
  __shared__ unsigned st[PSTCAP];
  __shared__ int loff[PTILE + 1];
  __shared__ int s_tile;
  // HW_REG_XCC_ID = hwreg id 20 (uniform within a block)
  unsigned xcd = __builtin_amdgcn_s_getreg((31u << 11) | 20u) & 7u;
  const int ntiles = (M + PTILE - 1) / PTILE;
  const int t = threadIdx.x;
  const int rg = t >> 1;  // row within tile (0..127)
  const int h = t & 1;    // feat half: feats [h*8, h*8+8) of the 16

#pragma unroll 1
  for (int d = 0; d < NCH; d++) {
    int p = (xcd + d) & 7;
    const unsigned short* plane = ybc + (size_t)p * M * 16;
    const float4 bb0 = *(const float4*)(bias + p * 16 + h * 8);
    const float4 bb1 = *(const float4*)(bias + p * 16 + h * 8 + 4);

#pragma unroll 1
    while (true) {
      if (t == 0) s_tile = atomicAdd(&q[p], 1);
      __syncthreads();
      int tile = s_tile;
      __syncthreads();
      if (tile >= ntiles) break;

      int base = tile * PTILE;
      if (t <= PTILE) {
        int idx = base + t;
        loff[t] = offsets[idx > M ? M : idx];
      }
      __syncthreads();
      int s0 = loff[0];
      int n = loff[PTILE] - s0;
      bool fits = (n <= PSTCAP);
      if (fits) {
        for (int i = t; i < n; i += 256)
          st[i] = __builtin_nontemporal_load(&rec4[s0 + i]);
      }
      __syncthreads();

      int r = base + rg;
      if (r < M) {
        int i0 = loff[rg] - s0, i1 = loff[rg + 1] - s0;
        float a0 = 0.f, a1 = 0.f, a2 = 0.f, a3 = 0.f;
        float a4 = 0.f, a5 = 0.f, a6 = 0.f, a7 = 0.f;
        float c0 = 0.f, c1 = 0.f, c2 = 0.f, c3 = 0.f;
        float c4 = 0.f, c5 = 0.f, c6 = 0.f, c7 = 0.f;
        const unsigned short* src = plane + h * 8;
        if (fits) {
          int i = i0;
          for (; i + 2 <= i1; i += 2) {
            unsigned q0 = st[i];
            unsigned q1 = st[i + 1];
            const uint4 u0 = *(const uint4*)(src + (size_t)(q0 >> 15) * 16);
            const uint4 u1 = *(const uint4*)(src + (size_t)(q1 >> 15) * 16);
            float v0 = __builtin_bit_cast(float, (q0 & 0x7fffu) << 16);
            float v1 = __builtin_bit_cast(float, (q1 & 0x7fffu) << 16);
            a0 += v0 * __builtin_bit_cast(float, u0.x << 16);
            a1 += v0 * __builtin_bit_cast(float, u0.x & 0xffff0000u);
            a2 += v0 * __builtin_bit_cast(float, u0.y << 16);
            a3 += v0 * __builtin_bit_cast(float, u0.y & 0xffff0000u);
            a4 += v0 * __builtin_bit_cast(float, u0.z << 16);
            a5 += v0 * __builtin_bit_cast(float, u0.z & 0xffff0000u);
            a6 += v0 * __builtin_bit_cast(float, u0.w << 16);
            a7 += v0 * __builtin_bit_cast(float, u0.w & 0xffff0000u);
            c0 += v1 * __builtin_bit_cast(float, u1.x << 16);
            c1 += v1 * __builtin_bit_cast(float, u1.x & 0xffff0000u);
            c2 += v1 * __builtin_bit_cast(float, u1.y << 16);
            c3 += v1 * __builtin_bit_cast(float, u1.y & 0xffff0000u);
            c4 += v1 * __builtin_bit_cast(float, u1.z << 16);
            c5 += v1 * __builtin_bit_cast(float, u1.z & 0xffff0000u);
            c6 += v1 * __builtin_bit_cast(float, u1.w << 16);
            c7 += v1 * __builtin_bit_cast(float, u1.w & 0xffff0000u);
          }
          if (i < i1) {
            unsigned q0 = st[i];
            const uint4 u0 = *(const uint4*)(src + (size_t)(q0 >> 15) * 16);
            float v0 = __builtin_bit_cast(float, (q0 & 0x7fffu) << 16);
            a0 += v0 * __builtin_bit_cast(float, u0.x << 16);
            a1 += v0 * __builtin_bit_cast(float, u0.x & 0xffff0000u);
            a2 += v0 * __builtin_bit_cast(float, u0.y << 16);
            a3 += v0 * __builtin_bit_cast(float, u0.y & 0xffff0000u);
            a4 += v0 * __builtin_bit_cast(float, u0.z << 16);
            a5 += v0 * __builtin_bit_cast(float, u0.z & 0xffff0000u);
            a6 += v0 * __builtin_bit_cast(float, u0.w << 16);
            a7 += v0 * __builtin_bit_cast(float, u0.w & 0xffff0000u);
          }
        } else {  // statistically never
          for (int i = i0; i < i1; i++) {
            unsigned q0 = rec4[s0 + i];
            const uint4 u0 = *(const uint4*)(src + (size_t)(q0 >> 15) * 16);
            float v0 = __builtin_bit_cast(float, (q0 & 0x7fffu) << 16);
            a0 += v0 * __builtin_bit_cast(float, u0.x << 16);
            a1 += v0 * __builtin_bit_cast(float, u0.x & 0xffff0000u);
            a2 += v0 * __builtin_bit_cast(float, u0.y << 16);
            a3 += v0 * __builtin_bit_cast(float, u0.y & 0xffff0000u);
            a4 += v0 * __builtin_bit_cast(float, u0.z << 16);
            a5 += v0 * __builtin_bit_cast(float, u0.z & 0xffff0000u);
            a6 += v0 * __builtin_bit_cast(float, u0.w << 16);
            a7 += v0 * __builtin_bit_cast(float, u0.w & 0xffff0000u);
          }
        }

        float* dst = out + (size_t)r * FOUT + p * 16 + h * 8;
        f32x4 o0, o1;
        o0[0] = fmaxf(a0 + c0 + bb0.x, 0.f);
        o0[1] = fmaxf(a1 + c1 + bb0.y, 0.f);
        o0[2] = fmaxf(a2 + c2 + bb0.z, 0.f);
        o0[3] = fmaxf(a3 + c3 + bb0.w, 0.f);
        o1[0] = fmaxf(a4 + c4 + bb1.x, 0.f);
        o1[1] = fmaxf(a5 + c5 + bb1.y, 0.f);
        o1[2] = fmaxf(a6 + c6 + bb1.z, 0.f);
        o1[3] = fmaxf(a7 + c7 + bb1.w, 0.f);
        __builtin_nontemporal_store(o0, (f32x4*)dst);
        __builtin_nontemporal_store(o1, (f32x4*)(dst + 4));
      }
      __syncthreads();
    }
  }
}

extern "C" void kernel_launch(void* const* d_in, const int* in_sizes, int n_in,
                              void* d_out, int out_size, void* d_ws, size_t ws_size,
                              hipStream_t stream) {
  const float* x = (const float*)d_in[0];
  const int* rows = (const int*)d_in[1];
  const int* cols = (const int*)d_in[2];
  const float* vals = (const float*)d_in[3];
  const float* theta = (const float*)d_in[4];
  const float* bias = (const float*)d_in[5];
  float* out = (float*)d_out;
  const int M = in_sizes[0] / FIN;       // 100000
  const int E = in_sizes[1];             // 3200000
  const int NT = (E + TILE - 1) / TILE;  // 391 tiles

  char* w = (char*)d_ws;
  auto alloc = [&](size_t bytes) {
    char* p = w;
    w += (bytes + 255) & ~(size_t)255;
    return p;
  };
  unsigned short* ybc = (unsigned short*)alloc((size_t)M * FOUT * 2);
  unsigned short* thetaT = (unsigned short*)alloc((size_t)FIN * FOUT * 2);
  unsigned* rec4tile = (unsigned*)alloc((size_t)NT * TILE * 4);
  unsigned char* rlotile = (unsigned char*)alloc((size_t)NT * TILE);
  int* lofs = (int*)alloc((size_t)NT * (NBK + 1) * 4);
  int* btotals = (int*)alloc((size_t)NBK * 4);
  int* boff = (int*)alloc((size_t)(NBK + 1) * 4);
  int* offsets = (int*)alloc((size_t)(M + 1) * 4);
  unsigned* rec4s = (unsigned*)alloc((size_t)E * 4);
  int* q = (int*)alloc((size_t)NCH * 4);

  hipMemsetAsync(btotals, 0, (size_t)NBK * 4, stream);
  prep_theta_k<<<(FIN * FOUT) / 256, 256, 0, stream>>>(theta, thetaT);
  gemm_k<<<(M + 127) / 128, 256, 0, stream>>>(x, thetaT, ybc, M);
  tilesort_k<<<NT, 256, 0, stream>>>(rows, cols, vals, rec4tile, rlotile, lofs, btotals, E);
  bscan_k<<<1, 1024, 0, stream>>>(btotals, boff, offsets, q, E, M);
  bsort_k<<<NBK, 256, 0, stream>>>(boff, lofs, rec4tile, rlotile, rec4s, offsets, NT, M);
  rowp_k<<<2048, 256, 0, stream>>>(offsets, rec4s, ybc, bias, out, q, M);
}

// Round 17
// 303.855 us; speedup vs baseline: 1.6450x; 1.6450x over previous
//
#include <hip/hip_runtime.h>
#include <stdint.h>
#include <stddef.h>

#define FIN 512
#define FOUT 128
#define BROWS 160      // rows per bucket -> NB = 625
#define NBK 625
#define SORT_CAP 7680  // LDS-staged records per bucket (mean 5120, sigma ~72)
#define TILE 8192      // edges per tilesort block
#define MAXNT 512      // fragment descriptor capacity (NT = 391)

typedef __attribute__((ext_vector_type(8))) short short8;
typedef __attribute__((ext_vector_type(4))) float f32x4;

__device__ __forceinline__ unsigned short f2bf(float f) {
  unsigned u = __builtin_bit_cast(unsigned, f);
  u = (u + 0x7fffu + ((u >> 16) & 1u)) >> 16;
  return (unsigned short)u;
}
__device__ __forceinline__ float bf2f(unsigned short h) {
  unsigned u = ((unsigned)h) << 16;
  return __builtin_bit_cast(float, u);
}
// packed f32x2 -> bf16x2 (RNE), single VALU op on gfx950
__device__ __forceinline__ unsigned cvtpk(float lo, float hi) {
  unsigned r;
  asm volatile("v_cvt_pk_bf16_f32 %0, %1, %2" : "=v"(r) : "v"(lo), "v"(hi));
  return r;
}

// theta [512][128] f32 -> thetaT [128][512] bf16
__global__ void prep_theta_k(const float* __restrict__ theta,
                             unsigned short* __restrict__ thetaT) {
  int idx = blockIdx.x * blockDim.x + threadIdx.x;  // 65536
  int n = idx >> 9;
  int k = idx & 511;
  thetaT[idx] = f2bf(theta[k * FOUT + n]);
}

// yb[M][128] bf16 = x[M][512] f32 @ thetaT^T, 16x16x32 MFMA, 128x128 tile.
// A-staging converts f32->bf16 via v_cvt_pk_bf16_f32 (8 ops vs ~70 manual).
__global__ __launch_bounds__(256) void gemm_k(const float* __restrict__ x,
                                              const unsigned short* __restrict__ thetaT,
                                              unsigned short* __restrict__ yb, int M) {
  __shared__ __align__(16) unsigned short lA[128 * 40];
  __shared__ __align__(16) unsigned short lB[128 * 40];
  const int tid = threadIdx.x;
  const int row0 = blockIdx.x * 128;
  const int wave = tid >> 6, lane = tid & 63;
  const int wm = wave >> 1, wn = wave & 1;
  const int fr = lane & 15, fq = lane >> 4;
  const int arow = tid >> 1, ahalf = tid & 1;

  f32x4 acc[4][4] = {};

  const int grow = row0 + arow;
  const bool aval = (grow < M);
  const float* asrc = x + (size_t)(aval ? grow : 0) * FIN + ahalf * 16;
  const unsigned short* bsrc = thetaT + (size_t)arow * FIN + ahalf * 16;

  for (int k0 = 0; k0 < FIN; k0 += 32) {
    float av[16];
    if (aval) {
      const float4* p = (const float4*)(asrc + k0);
      float4 v0 = p[0], v1 = p[1], v2 = p[2], v3 = p[3];
      av[0] = v0.x; av[1] = v0.y; av[2] = v0.z; av[3] = v0.w;
      av[4] = v1.x; av[5] = v1.y; av[6] = v1.z; av[7] = v1.w;
      av[8] = v2.x; av[9] = v2.y; av[10] = v2.z; av[11] = v2.w;
      av[12] = v3.x; av[13] = v3.y; av[14] = v3.z; av[15] = v3.w;
    } else {
      for (int i = 0; i < 16; i++) av[i] = 0.f;
    }
    unsigned ap[8];
#pragma unroll
    for (int i = 0; i < 8; i++) ap[i] = cvtpk(av[2 * i], av[2 * i + 1]);
    uint4* aw = (uint4*)&lA[arow * 40 + ahalf * 16];
    aw[0] = make_uint4(ap[0], ap[1], ap[2], ap[3]);
    aw[1] = make_uint4(ap[4], ap[5], ap[6], ap[7]);

    const uint4* bp = (const uint4*)(bsrc + k0);
    uint4 b0 = bp[0], b1 = bp[1];
    uint4* bw = (uint4*)&lB[arow * 40 + ahalf * 16];
    bw[0] = b0; bw[1] = b1;

    __syncthreads();

    short8 af[4], bfv[4];
#pragma unroll
    for (int m = 0; m < 4; m++)
      af[m] = *(const short8*)&lA[(wm * 64 + m * 16 + fr) * 40 + fq * 8];
#pragma unroll
    for (int n = 0; n < 4; n++)
      bfv[n] = *(const short8*)&lB[(wn * 64 + n * 16 + fr) * 40 + fq * 8];
#pragma unroll
    for (int m = 0; m < 4; m++)
#pragma unroll
      for (int n = 0; n < 4; n++)
        acc[m][n] = __builtin_amdgcn_mfma_f32_16x16x32_bf16(af[m], bfv[n], acc[m][n], 0, 0, 0);

    __syncthreads();
  }

  // C/D layout: col = lane&15, row = (lane>>4)*4 + reg
#pragma unroll
  for (int m = 0; m < 4; m++) {
    int rbase = row0 + wm * 64 + m * 16 + fq * 4;
#pragma unroll
    for (int j = 0; j < 4; j++) {
      int r = rbase + j;
      if (r < M) {
        unsigned short* dst = yb + (size_t)r * FOUT + wn * 64;
#pragma unroll
        for (int n = 0; n < 4; n++) dst[n * 16 + fr] = f2bf(acc[m][n][j]);
      }
    }
  }
}

// tilesort: per 8192-edge tile, LDS count-sort by bucket, dump contiguous.
// Also accumulates per-bucket global totals.
__global__ __launch_bounds__(256) void tilesort_k(const int* __restrict__ rows,
                                                  const int* __restrict__ cols,
                                                  const float* __restrict__ vals,
                                                  unsigned* __restrict__ rec4tile,
                                                  unsigned char* __restrict__ rlotile,
                                                  int* __restrict__ lofs,
                                                  int* __restrict__ btotals, int E) {
  __shared__ int hist[NBK];
  __shared__ int wsum[4];
  __shared__ unsigned srec[TILE];
  __shared__ unsigned char srlo[TILE];
  const int c = blockIdx.x, t = threadIdx.x;
  const int base = c * TILE;
  const int n = (E - base < TILE) ? (E - base) : TILE;

  for (int i = t; i < NBK; i += 256) hist[i] = 0;
  __syncthreads();

#pragma unroll
  for (int k = 0; k < TILE / 256; k++) {
    int i = base + k * 256 + t;
    if (i < E) atomicAdd(&hist[rows[i] / BROWS], 1);
  }
  __syncthreads();

  int c0 = t * 3, c1 = c0 + 1, c2 = c0 + 2;
  int h0 = (c0 < NBK) ? hist[c0] : 0;
  int h1 = (c1 < NBK) ? hist[c1] : 0;
  int h2 = (c2 < NBK) ? hist[c2] : 0;
  if (h0) atomicAdd(&btotals[c0], h0);
  if (h1) atomicAdd(&btotals[c1], h1);
  if (h2) atomicAdd(&btotals[c2], h2);
  int loc = h0 + h1 + h2;
  int lane = t & 63, wv = t >> 6;
  int inc = loc;
  for (int off = 1; off < 64; off <<= 1) {
    int u = __shfl_up(inc, off, 64);
    if (lane >= off) inc += u;
  }
  if (lane == 63) wsum[wv] = inc;
  __syncthreads();
  int excl = inc - loc;
  for (int i = 0; i < 4; i++)
    if (i < wv) excl += wsum[i];

  size_t lbase = (size_t)c * (NBK + 1);
  int e = excl;
  if (c0 <= NBK) lofs[lbase + c0] = e;
  __syncthreads();  // hist reads done everywhere before cursor overwrite
  if (c0 < NBK) hist[c0] = e;
  e += h0;
  if (c1 <= NBK) lofs[lbase + c1] = e;
  if (c1 < NBK) hist[c1] = e;
  e += h1;
  if (c2 <= NBK) lofs[lbase + c2] = e;
  if (c2 < NBK) hist[c2] = e;
  __syncthreads();

#pragma unroll
  for (int k = 0; k < TILE / 256; k++) {
    int i = base + k * 256 + t;
    if (i < E) {
      int r = rows[i];
      int b = r / BROWS;
      int p = atomicAdd(&hist[b], 1);
      srec[p] = ((unsigned)cols[i] << 15) | ((unsigned)f2bf(vals[i]) & 0x7fffu);
      srlo[p] = (unsigned char)(r - b * BROWS);
    }
  }
  __syncthreads();

  for (int j = t; j < n; j += 256) {
    rec4tile[base + j] = srec[j];
    rlotile[base + j] = srlo[j];
  }
}

// single-block exclusive scan of 625 bucket totals -> boff; sentinels
__global__ __launch_bounds__(1024) void bscan_k(const int* __restrict__ btotals,
                                                int* __restrict__ boff,
                                                int* __restrict__ offsets,
                                                int E, int M) {
  __shared__ int tmp[1024];
  int t = threadIdx.x;
  tmp[t] = (t < NBK) ? btotals[t] : 0;
  __syncthreads();
  for (int off = 1; off < 1024; off <<= 1) {
    int v = (t >= off) ? tmp[t - off] : 0;
    __syncthreads();
    tmp[t] += v;
    __syncthreads();
  }
  if (t < NBK) boff[t] = t ? tmp[t - 1] : 0;
  if (t == 0) {
    boff[NBK] = E;
    offsets[M] = E;
  }
}

// per-bucket: coalesced fragment gather (16-lane groups), LDS count-sort by
// rlo, write sorted bucket + per-row CSR offsets.
__global__ __launch_bounds__(256) void bsort_k(const int* __restrict__ boff,
                                               const int* __restrict__ lofs,
                                               const unsigned* __restrict__ rec4tile,
                                               const unsigned char* __restrict__ rlotile,
                                               unsigned* __restrict__ rec4s,
                                               int* __restrict__ offsets,
                                               int NT, int M) {
  __shared__ unsigned s4[SORT_CAP];
  __shared__ unsigned char k8[SORT_CAP];
  __shared__ int lh[256];
  __shared__ int lsc[256];
  __shared__ int wsum[4];
  __shared__ int fsrc[MAXNT];
  __shared__ int fdst[MAXNT];
  __shared__ int flen[MAXNT];
  int b = blockIdx.x, t = threadIdx.x;
  int start = boff[b];

  int ca = 2 * t, cb = 2 * t + 1;
  int la = 0, fa = 0, lb2 = 0, fb = 0;
  if (ca < NT) {
    size_t p = (size_t)ca * (NBK + 1) + b;
    la = lofs[p];
    fa = lofs[p + 1] - la;
  }
  if (cb < NT) {
    size_t p = (size_t)cb * (NBK + 1) + b;
    lb2 = lofs[p];
    fb = lofs[p + 1] - lb2;
  }
  int loc = fa + fb;
  int lane = t & 63, wv = t >> 6;
  int inc = loc;
  for (int off = 1; off < 64; off <<= 1) {
    int u = __shfl_up(inc, off, 64);
    if (lane >= off) inc += u;
  }
  if (lane == 63) wsum[wv] = inc;
  __syncthreads();
  int excl = inc - loc;
  for (int i = 0; i < 4; i++)
    if (i < wv) excl += wsum[i];

  if (ca < NT) {
    fsrc[ca] = ca * TILE + la;
    fdst[ca] = excl;
    flen[ca] = fa;
  }
  if (cb < NT) {
    fsrc[cb] = cb * TILE + lb2;
    fdst[cb] = excl + fa;
    flen[cb] = fb;
  }
  lh[t] = 0;
  __syncthreads();

  int grp = t >> 4, l16 = t & 15;
  for (int f = grp; f < NT; f += 16) {
    int L = flen[f];
    int sd = fdst[f];
    int ss = fsrc[f];
    for (int j = l16; j < L; j += 16) {
      int d = sd + j;
      if (d < SORT_CAP) {
        s4[d] = rec4tile[ss + j];
        k8[d] = rlotile[ss + j];
      }
    }
  }

  int n = boff[b + 1] - start;
  if (n > SORT_CAP) n = SORT_CAP;  // statistically impossible (>35 sigma)
  __syncthreads();

  for (int i = t; i < n; i += 256) atomicAdd(&lh[k8[i]], 1);
  __syncthreads();
  lsc[t] = lh[t];
  __syncthreads();
  for (int off = 1; off < 256; off <<= 1) {
    int v = (t >= off) ? lsc[t - off] : 0;
    __syncthreads();
    lsc[t] += v;
    __syncthreads();
  }
  int ex = t ? lsc[t - 1] : 0;
  int row = b * BROWS + t;
  if (t < BROWS && row < M) offsets[row] = start + ex;
  lh[t] = ex;  // reuse as cursor
  __syncthreads();
  for (int i = t; i < n; i += 256) {
    unsigned r = s4[i];
    int p = atomicAdd(&lh[k8[i]], 1);
    rec4s[start + p] = r;
  }
}

// row phase: 16 lanes per row (lane covers 8 feats = one uint4 load / edge),
// edge loop unrolled x2 with independent accumulator sets. Fused bias+relu.
__global__ __launch_bounds__(256) void rowv2_k(const int* __restrict__ offsets,
                                               const unsigned* __restrict__ rec4,
                                               const unsigned short* __restrict__ yb,
                                               const float* __restrict__ bias,
                                               float* __restrict__ out, int M) {
  int gid = blockIdx.x * blockDim.x + threadIdx.x;
  int r = gid >> 4;  // 16 lanes/row
  int l = gid & 15;  // feats [l*8, l*8+8)
  if (r >= M) return;
  int s = offsets[r], e = offsets[r + 1];
  const unsigned short* src = yb + l * 8;

  float a0 = 0.f, a1 = 0.f, a2 = 0.f, a3 = 0.f, a4 = 0.f, a5 = 0.f, a6 = 0.f, a7 = 0.f;
  float c0 = 0.f, c1 = 0.f, c2 = 0.f, c3 = 0.f, c4 = 0.f, c5 = 0.f, c6 = 0.f, c7 = 0.f;

  int i = s;
  for (; i + 2 <= e; i += 2) {
    unsigned q0 = rec4[i];
    unsigned q1 = rec4[i + 1];
    const uint4 u0 = *(const uint4*)(src + (size_t)(q0 >> 15) * FOUT);
    const uint4 u1 = *(const uint4*)(src + (size_t)(q1 >> 15) * FOUT);
    float v0 = __builtin_bit_cast(float, (q0 & 0x7fffu) << 16);
    float v1 = __builtin_bit_cast(float, (q1 & 0x7fffu) << 16);
    a0 += v0 * __builtin_bit_cast(float, u0.x << 16);
    a1 += v0 * __builtin_bit_cast(float, u0.x & 0xffff0000u);
    a2 += v0 * __builtin_bit_cast(float, u0.y << 16);
    a3 += v0 * __builtin_bit_cast(float, u0.y & 0xffff0000u);
    a4 += v0 * __builtin_bit_cast(float, u0.z << 16);
    a5 += v0 * __builtin_bit_cast(float, u0.z & 0xffff0000u);
    a6 += v0 * __builtin_bit_cast(float, u0.w << 16);
    a7 += v0 * __builtin_bit_cast(float, u0.w & 0xffff0000u);
    c0 += v1 * __builtin_bit_cast(float, u1.x << 16);
    c1 += v1 * __builtin_bit_cast(float, u1.x & 0xffff0000u);
    c2 += v1 * __builtin_bit_cast(float, u1.y << 16);
    c3 += v1 * __builtin_bit_cast(float, u1.y & 0xffff0000u);
    c4 += v1 * __builtin_bit_cast(float, u1.z << 16);
    c5 += v1 * __builtin_bit_cast(float, u1.z & 0xffff0000u);
    c6 += v1 * __builtin_bit_cast(float, u1.w << 16);
    c7 += v1 * __builtin_bit_cast(float, u1.w & 0xffff0000u);
  }
  if (i < e) {
    unsigned q0 = rec4[i];
    const uint4 u0 = *(const uint4*)(src + (size_t)(q0 >> 15) * FOUT);
    float v0 = __builtin_bit_cast(float, (q0 & 0x7fffu) << 16);
    a0 += v0 * __builtin_bit_cast(float, u0.x << 16);
    a1 += v0 * __builtin_bit_cast(float, u0.x & 0xffff0000u);
    a2 += v0 * __builtin_bit_cast(float, u0.y << 16);
    a3 += v0 * __builtin_bit_cast(float, u0.y & 0xffff0000u);
    a4 += v0 * __builtin_bit_cast(float, u0.z << 16);
    a5 += v0 * __builtin_bit_cast(float, u0.z & 0xffff0000u);
    a6 += v0 * __builtin_bit_cast(float, u0.w << 16);
    a7 += v0 * __builtin_bit_cast(float, u0.w & 0xffff0000u);
  }

  const float4 b0 = *(const float4*)(bias + l * 8);
  const float4 b1 = *(const float4*)(bias + l * 8 + 4);
  float* dst = out + (size_t)r * FOUT + l * 8;
  float4 o0, o1;
  o0.x = fmaxf(a0 + c0 + b0.x, 0.f);
  o0.y = fmaxf(a1 + c1 + b0.y, 0.f);
  o0.z = fmaxf(a2 + c2 + b0.z, 0.f);
  o0.w = fmaxf(a3 + c3 + b0.w, 0.f);
  o1.x = fmaxf(a4 + c4 + b1.x, 0.f);
  o1.y = fmaxf(a5 + c5 + b1.y, 0.f);
  o1.z = fmaxf(a6 + c6 + b1.z, 0.f);
  o1.w = fmaxf(a7 + c7 + b1.w, 0.f);
  *(float4*)(dst) = o0;
  *(float4*)(dst + 4) = o1;
}

extern "C" void kernel_launch(void* const* d_in, const int* in_sizes, int n_in,
                              void* d_out, int out_size, void* d_ws, size_t ws_size,
                              hipStream_t stream) {
  const float* x = (const float*)d_in[0];
  const int* rows = (const int*)d_in[1];
  const int* cols = (const int*)d_in[2];
  const float* vals = (const float*)d_in[3];
  const float* theta = (const float*)d_in[4];
  const float* bias = (const float*)d_in[5];
  float* out = (float*)d_out;
  const int M = in_sizes[0] / FIN;       // 100000
  const int E = in_sizes[1];             // 3200000
  const int NT = (E + TILE - 1) / TILE;  // 391 tiles

  char* w = (char*)d_ws;
  auto alloc = [&](size_t bytes) {
    char* p = w;
    w += (bytes + 255) & ~(size_t)255;
    return p;
  };
  unsigned short* yb = (unsigned short*)alloc((size_t)M * FOUT * 2);
  unsigned short* thetaT = (unsigned short*)alloc((size_t)FIN * FOUT * 2);
  unsigned* rec4tile = (unsigned*)alloc((size_t)NT * TILE * 4);
  unsigned char* rlotile = (unsigned char*)alloc((size_t)NT * TILE);
  int* lofs = (int*)alloc((size_t)NT * (NBK + 1) * 4);
  int* btotals = (int*)alloc((size_t)NBK * 4);
  int* boff = (int*)alloc((size_t)(NBK + 1) * 4);
  int* offsets = (int*)alloc((size_t)(M + 1) * 4);
  unsigned* rec4s = (unsigned*)alloc((size_t)E * 4);

  hipMemsetAsync(btotals, 0, (size_t)NBK * 4, stream);
  prep_theta_k<<<(FIN * FOUT) / 256, 256, 0, stream>>>(theta, thetaT);
  gemm_k<<<(M + 127) / 128, 256, 0, stream>>>(x, thetaT, yb, M);
  tilesort_k<<<NT, 256, 0, stream>>>(rows, cols, vals, rec4tile, rlotile, lofs, btotals, E);
  bscan_k<<<1, 1024, 0, stream>>>(btotals, boff, offsets, E, M);
  bsort_k<<<NBK, 256, 0, stream>>>(boff, lofs, rec4tile, rlotile, rec4s, offsets, NT, M);
  rowv2_k<<<(M * 16 + 255) / 256, 256, 0, stream>>>(offsets, rec4s, yb, bias, out, M);
}

// Round 18
// 299.601 us; speedup vs baseline: 1.6684x; 1.0142x over previous
//
#include <hip/hip_runtime.h>
#include <stdint.h>
#include <stddef.h>

#define FIN 512
#define FOUT 128
#define BROWS 128      // rows per bucket -> NBK = 782
#define NBK 782
#define SORT_CAP 5120  // LDS-staged records per bucket (mean 4096, +16 sigma)
#define TILE 8192      // edges per tilesort block
#define MAXNT 512      // fragment descriptor capacity (NT = 391)

typedef __attribute__((ext_vector_type(8))) short short8;
typedef __attribute__((ext_vector_type(4))) float f32x4;

__device__ __forceinline__ unsigned short f2bf(float f) {
  unsigned u = __builtin_bit_cast(unsigned, f);
  u = (u + 0x7fffu + ((u >> 16) & 1u)) >> 16;
  return (unsigned short)u;
}
__device__ __forceinline__ float bf2f(unsigned short h) {
  unsigned u = ((unsigned)h) << 16;
  return __builtin_bit_cast(float, u);
}

// theta [512][128] f32 -> thetaT [128][512] bf16
__global__ void prep_theta_k(const float* __restrict__ theta,
                             unsigned short* __restrict__ thetaT) {
  int idx = blockIdx.x * blockDim.x + threadIdx.x;  // 65536
  int n = idx >> 9;
  int k = idx & 511;
  thetaT[idx] = f2bf(theta[k * FOUT + n]);
}

// yb[M][128] bf16 = x[M][512] f32 @ thetaT^T, 16x16x32 MFMA, 128x128 tile.
__global__ __launch_bounds__(256) void gemm_k(const float* __restrict__ x,
                                              const unsigned short* __restrict__ thetaT,
                                              unsigned short* __restrict__ yb, int M) {
  __shared__ __align__(16) unsigned short lA[128 * 40];
  __shared__ __align__(16) unsigned short lB[128 * 40];
  const int tid = threadIdx.x;
  const int row0 = blockIdx.x * 128;
  const int wave = tid >> 6, lane = tid & 63;
  const int wm = wave >> 1, wn = wave & 1;
  const int fr = lane & 15, fq = lane >> 4;
  const int arow = tid >> 1, ahalf = tid & 1;

  f32x4 acc[4][4] = {};

  const int grow = row0 + arow;
  const bool aval = (grow < M);
  const float* asrc = x + (size_t)(aval ? grow : 0) * FIN + ahalf * 16;
  const unsigned short* bsrc = thetaT + (size_t)arow * FIN + ahalf * 16;

  for (int k0 = 0; k0 < FIN; k0 += 32) {
    float av[16];
    if (aval) {
      const float4* p = (const float4*)(asrc + k0);
      float4 v0 = p[0], v1 = p[1], v2 = p[2], v3 = p[3];
      av[0] = v0.x; av[1] = v0.y; av[2] = v0.z; av[3] = v0.w;
      av[4] = v1.x; av[5] = v1.y; av[6] = v1.z; av[7] = v1.w;
      av[8] = v2.x; av[9] = v2.y; av[10] = v2.z; av[11] = v2.w;
      av[12] = v3.x; av[13] = v3.y; av[14] = v3.z; av[15] = v3.w;
    } else {
      for (int i = 0; i < 16; i++) av[i] = 0.f;
    }
    unsigned ap[8];
    for (int i = 0; i < 8; i++)
      ap[i] = (unsigned)f2bf(av[2 * i]) | ((unsigned)f2bf(av[2 * i + 1]) << 16);
    uint4* aw = (uint4*)&lA[arow * 40 + ahalf * 16];
    aw[0] = make_uint4(ap[0], ap[1], ap[2], ap[3]);
    aw[1] = make_uint4(ap[4], ap[5], ap[6], ap[7]);

    const uint4* bp = (const uint4*)(bsrc + k0);
    uint4 b0 = bp[0], b1 = bp[1];
    uint4* bw = (uint4*)&lB[arow * 40 + ahalf * 16];
    bw[0] = b0; bw[1] = b1;

    __syncthreads();

    short8 af[4], bfv[4];
#pragma unroll
    for (int m = 0; m < 4; m++)
      af[m] = *(const short8*)&lA[(wm * 64 + m * 16 + fr) * 40 + fq * 8];
#pragma unroll
    for (int n = 0; n < 4; n++)
      bfv[n] = *(const short8*)&lB[(wn * 64 + n * 16 + fr) * 40 + fq * 8];
#pragma unroll
    for (int m = 0; m < 4; m++)
#pragma unroll
      for (int n = 0; n < 4; n++)
        acc[m][n] = __builtin_amdgcn_mfma_f32_16x16x32_bf16(af[m], bfv[n], acc[m][n], 0, 0, 0);

    __syncthreads();
  }

  // C/D layout: col = lane&15, row = (lane>>4)*4 + reg
#pragma unroll
  for (int m = 0; m < 4; m++) {
    int rbase = row0 + wm * 64 + m * 16 + fq * 4;
#pragma unroll
    for (int j = 0; j < 4; j++) {
      int r = rbase + j;
      if (r < M) {
        unsigned short* dst = yb + (size_t)r * FOUT + wn * 64;
#pragma unroll
        for (int n = 0; n < 4; n++) dst[n * 16 + fr] = f2bf(acc[m][n][j]);
      }
    }
  }
}

// tilesort: per 8192-edge tile, LDS count-sort by bucket, dump contiguous.
// Also accumulates per-bucket global totals.
__global__ __launch_bounds__(256) void tilesort_k(const int* __restrict__ rows,
                                                  const int* __restrict__ cols,
                                                  const float* __restrict__ vals,
                                                  unsigned* __restrict__ rec4tile,
                                                  unsigned char* __restrict__ rlotile,
                                                  int* __restrict__ lofs,
                                                  int* __restrict__ btotals, int E) {
  __shared__ int hist[NBK];
  __shared__ int wsum[4];
  __shared__ unsigned srec[TILE];
  __shared__ unsigned char srlo[TILE];
  const int c = blockIdx.x, t = threadIdx.x;
  const int base = c * TILE;
  const int n = (E - base < TILE) ? (E - base) : TILE;

  for (int i = t; i < NBK; i += 256) hist[i] = 0;
  __syncthreads();

#pragma unroll
  for (int k = 0; k < TILE / 256; k++) {
    int i = base + k * 256 + t;
    if (i < E) atomicAdd(&hist[rows[i] / BROWS], 1);
  }
  __syncthreads();

  // exclusive scan of hist[0..NBK-1]; 4 entries/thread (1024 >= 783)
  int c0 = t * 4, c1 = c0 + 1, c2 = c0 + 2, c3 = c0 + 3;
  int h0 = (c0 < NBK) ? hist[c0] : 0;
  int h1 = (c1 < NBK) ? hist[c1] : 0;
  int h2 = (c2 < NBK) ? hist[c2] : 0;
  int h3 = (c3 < NBK) ? hist[c3] : 0;
  // fold per-bucket totals to global
  if (h0) atomicAdd(&btotals[c0], h0);
  if (h1) atomicAdd(&btotals[c1], h1);
  if (h2) atomicAdd(&btotals[c2], h2);
  if (h3) atomicAdd(&btotals[c3], h3);
  int loc = h0 + h1 + h2 + h3;
  int lane = t & 63, wv = t >> 6;
  int inc = loc;
  for (int off = 1; off < 64; off <<= 1) {
    int u = __shfl_up(inc, off, 64);
    if (lane >= off) inc += u;
  }
  if (lane == 63) wsum[wv] = inc;
  __syncthreads();
  int excl = inc - loc;
  for (int i = 0; i < 4; i++)
    if (i < wv) excl += wsum[i];

  size_t lbase = (size_t)c * (NBK + 1);
  int e = excl;
  if (c0 <= NBK) lofs[lbase + c0] = e;
  __syncthreads();  // hist reads done everywhere before cursor overwrite
  if (c0 < NBK) hist[c0] = e;
  e += h0;
  if (c1 <= NBK) lofs[lbase + c1] = e;
  if (c1 < NBK) hist[c1] = e;
  e += h1;
  if (c2 <= NBK) lofs[lbase + c2] = e;
  if (c2 < NBK) hist[c2] = e;
  e += h2;
  if (c3 <= NBK) lofs[lbase + c3] = e;
  if (c3 < NBK) hist[c3] = e;
  __syncthreads();

#pragma unroll
  for (int k = 0; k < TILE / 256; k++) {
    int i = base + k * 256 + t;
    if (i < E) {
      int r = rows[i];
      int b = r / BROWS;
      int p = atomicAdd(&hist[b], 1);
      srec[p] = ((unsigned)cols[i] << 15) | ((unsigned)f2bf(vals[i]) & 0x7fffu);
      srlo[p] = (unsigned char)(r - b * BROWS);
    }
  }
  __syncthreads();

  for (int j = t; j < n; j += 256) {
    rec4tile[base + j] = srec[j];
    rlotile[base + j] = srlo[j];
  }
}

// single-block exclusive scan of NBK bucket totals -> boff; sentinels
__global__ __launch_bounds__(1024) void bscan_k(const int* __restrict__ btotals,
                                                int* __restrict__ boff,
                                                int* __restrict__ offsets,
                                                int E, int M) {
  __shared__ int tmp[1024];
  int t = threadIdx.x;
  tmp[t] = (t < NBK) ? btotals[t] : 0;
  __syncthreads();
  for (int off = 1; off < 1024; off <<= 1) {
    int v = (t >= off) ? tmp[t - off] : 0;
    __syncthreads();
    tmp[t] += v;
    __syncthreads();
  }
  if (t < NBK) boff[t] = t ? tmp[t - 1] : 0;
  if (t == 0) {
    boff[NBK] = E;
    offsets[M] = E;
  }
}

// per-bucket: coalesced fragment gather (16-lane groups), LDS count-sort by
// rlo, write sorted bucket + per-row CSR offsets.
__global__ __launch_bounds__(256) void bsort_k(const int* __restrict__ boff,
                                               const int* __restrict__ lofs,
                                               const unsigned* __restrict__ rec4tile,
                                               const unsigned char* __restrict__ rlotile,
                                               unsigned* __restrict__ rec4s,
                                               int* __restrict__ offsets,
                                               int NT, int M) {
  __shared__ unsigned s4[SORT_CAP];
  __shared__ unsigned char k8[SORT_CAP];
  __shared__ int lh[256];
  __shared__ int lsc[256];
  __shared__ int wsum[4];
  __shared__ int fsrc[MAXNT];
  __shared__ int fdst[MAXNT];
  __shared__ int flen[MAXNT];
  int b = blockIdx.x, t = threadIdx.x;
  int start = boff[b];

  // fragment descriptors: 2 fragments per thread (tiles 2t, 2t+1)
  int ca = 2 * t, cb = 2 * t + 1;
  int la = 0, fa = 0, lb2 = 0, fb = 0;
  if (ca < NT) {
    size_t p = (size_t)ca * (NBK + 1) + b;
    la = lofs[p];
    fa = lofs[p + 1] - la;
  }
  if (cb < NT) {
    size_t p = (size_t)cb * (NBK + 1) + b;
    lb2 = lofs[p];
    fb = lofs[p + 1] - lb2;
  }
  int loc = fa + fb;
  int lane = t & 63, wv = t >> 6;
  int inc = loc;
  for (int off = 1; off < 64; off <<= 1) {
    int u = __shfl_up(inc, off, 64);
    if (lane >= off) inc += u;
  }
  if (lane == 63) wsum[wv] = inc;
  __syncthreads();
  int excl = inc - loc;
  for (int i = 0; i < 4; i++)
    if (i < wv) excl += wsum[i];

  if (ca < NT) {
    fsrc[ca] = ca * TILE + la;
    fdst[ca] = excl;
    flen[ca] = fa;
  }
  if (cb < NT) {
    fsrc[cb] = cb * TILE + lb2;
    fdst[cb] = excl + fa;
    flen[cb] = fb;
  }
  lh[t] = 0;
  __syncthreads();

  // coalesced copy: 16 lane-groups, one fragment per group per iteration
  int grp = t >> 4, l16 = t & 15;
  for (int f = grp; f < NT; f += 16) {
    int L = flen[f];
    int sd = fdst[f];
    int ss = fsrc[f];
    for (int j = l16; j < L; j += 16) {
      int d = sd + j;
      if (d < SORT_CAP) {
        s4[d] = rec4tile[ss + j];
        k8[d] = rlotile[ss + j];
      }
    }
  }

  int n = boff[b + 1] - start;
  if (n > SORT_CAP) n = SORT_CAP;  // statistically impossible (>16 sigma)
  __syncthreads();

  // count-sort by rlo (keys < BROWS=128)
  for (int i = t; i < n; i += 256) atomicAdd(&lh[k8[i]], 1);
  __syncthreads();
  lsc[t] = lh[t];
  __syncthreads();
  for (int off = 1; off < 256; off <<= 1) {
    int v = (t >= off) ? lsc[t - off] : 0;
    __syncthreads();
    lsc[t] += v;
    __syncthreads();
  }
  int ex = t ? lsc[t - 1] : 0;
  int row = b * BROWS + t;
  if (t < BROWS && row < M) offsets[row] = start + ex;
  lh[t] = ex;  // reuse as cursor
  __syncthreads();
  for (int i = t; i < n; i += 256) {
    unsigned r = s4[i];
    int p = atomicAdd(&lh[k8[i]], 1);
    rec4s[start + p] = r;
  }
}

// row phase: 16 lanes per row (lane covers 8 feats = one uint4 load / edge),
// edge loop unrolled x2 with independent accumulator sets. Fused bias+relu.
__global__ __launch_bounds__(256) void rowv2_k(const int* __restrict__ offsets,
                                               const unsigned* __restrict__ rec4,
                                               const unsigned short* __restrict__ yb,
                                               const float* __restrict__ bias,
                                               float* __restrict__ out, int M) {
  int gid = blockIdx.x * blockDim.x + threadIdx.x;
  int r = gid >> 4;  // 16 lanes/row
  int l = gid & 15;  // feats [l*8, l*8+8)
  if (r >= M) return;
  int s = offsets[r], e = offsets[r + 1];
  const unsigned short* src = yb + l * 8;

  float a0 = 0.f, a1 = 0.f, a2 = 0.f, a3 = 0.f, a4 = 0.f, a5 = 0.f, a6 = 0.f, a7 = 0.f;
  float c0 = 0.f, c1 = 0.f, c2 = 0.f, c3 = 0.f, c4 = 0.f, c5 = 0.f, c6 = 0.f, c7 = 0.f;

  int i = s;
  for (; i + 2 <= e; i += 2) {
    unsigned q0 = rec4[i];
    unsigned q1 = rec4[i + 1];
    const uint4 u0 = *(const uint4*)(src + (size_t)(q0 >> 15) * FOUT);
    const uint4 u1 = *(const uint4*)(src + (size_t)(q1 >> 15) * FOUT);
    float v0 = __builtin_bit_cast(float, (q0 & 0x7fffu) << 16);
    float v1 = __builtin_bit_cast(float, (q1 & 0x7fffu) << 16);
    a0 += v0 * __builtin_bit_cast(float, u0.x << 16);
    a1 += v0 * __builtin_bit_cast(float, u0.x & 0xffff0000u);
    a2 += v0 * __builtin_bit_cast(float, u0.y << 16);
    a3 += v0 * __builtin_bit_cast(float, u0.y & 0xffff0000u);
    a4 += v0 * __builtin_bit_cast(float, u0.z << 16);
    a5 += v0 * __builtin_bit_cast(float, u0.z & 0xffff0000u);
    a6 += v0 * __builtin_bit_cast(float, u0.w << 16);
    a7 += v0 * __builtin_bit_cast(float, u0.w & 0xffff0000u);
    c0 += v1 * __builtin_bit_cast(float, u1.x << 16);
    c1 += v1 * __builtin_bit_cast(float, u1.x & 0xffff0000u);
    c2 += v1 * __builtin_bit_cast(float, u1.y << 16);
    c3 += v1 * __builtin_bit_cast(float, u1.y & 0xffff0000u);
    c4 += v1 * __builtin_bit_cast(float, u1.z << 16);
    c5 += v1 * __builtin_bit_cast(float, u1.z & 0xffff0000u);
    c6 += v1 * __builtin_bit_cast(float, u1.w << 16);
    c7 += v1 * __builtin_bit_cast(float, u1.w & 0xffff0000u);
  }
  if (i < e) {
    unsigned q0 = rec4[i];
    const uint4 u0 = *(const uint4*)(src + (size_t)(q0 >> 15) * FOUT);
    float v0 = __builtin_bit_cast(float, (q0 & 0x7fffu) << 16);
    a0 += v0 * __builtin_bit_cast(float, u0.x << 16);
    a1 += v0 * __builtin_bit_cast(float, u0.x & 0xffff0000u);
    a2 += v0 * __builtin_bit_cast(float, u0.y << 16);
    a3 += v0 * __builtin_bit_cast(float, u0.y & 0xffff0000u);
    a4 += v0 * __builtin_bit_cast(float, u0.z << 16);
    a5 += v0 * __builtin_bit_cast(float, u0.z & 0xffff0000u);
    a6 += v0 * __builtin_bit_cast(float, u0.w << 16);
    a7 += v0 * __builtin_bit_cast(float, u0.w & 0xffff0000u);
  }

  const float4 b0 = *(const float4*)(bias + l * 8);
  const float4 b1 = *(const float4*)(bias + l * 8 + 4);
  float* dst = out + (size_t)r * FOUT + l * 8;
  float4 o0, o1;
  o0.x = fmaxf(a0 + c0 + b0.x, 0.f);
  o0.y = fmaxf(a1 + c1 + b0.y, 0.f);
  o0.z = fmaxf(a2 + c2 + b0.z, 0.f);
  o0.w = fmaxf(a3 + c3 + b0.w, 0.f);
  o1.x = fmaxf(a4 + c4 + b1.x, 0.f);
  o1.y = fmaxf(a5 + c5 + b1.y, 0.f);
  o1.z = fmaxf(a6 + c6 + b1.z, 0.f);
  o1.w = fmaxf(a7 + c7 + b1.w, 0.f);
  *(float4*)(dst) = o0;
  *(float4*)(dst + 4) = o1;
}

extern "C" void kernel_launch(void* const* d_in, const int* in_sizes, int n_in,
                              void* d_out, int out_size, void* d_ws, size_t ws_size,
                              hipStream_t stream) {
  const float* x = (const float*)d_in[0];
  const int* rows = (const int*)d_in[1];
  const int* cols = (const int*)d_in[2];
  const float* vals = (const float*)d_in[3];
  const float* theta = (const float*)d_in[4];
  const float* bias = (const float*)d_in[5];
  float* out = (float*)d_out;
  const int M = in_sizes[0] / FIN;       // 100000
  const int E = in_sizes[1];             // 3200000
  const int NT = (E + TILE - 1) / TILE;  // 391 tiles

  char* w = (char*)d_ws;
  auto alloc = [&](size_t bytes) {
    char* p = w;
    w += (bytes + 255) & ~(size_t)255;
    return p;
  };
  unsigned short* yb = (unsigned short*)alloc((size_t)M * FOUT * 2);
  unsigned short* thetaT = (unsigned short*)alloc((size_t)FIN * FOUT * 2);
  unsigned* rec4tile = (unsigned*)alloc((size_t)NT * TILE * 4);
  unsigned char* rlotile = (unsigned char*)alloc((size_t)NT * TILE);
  int* lofs = (int*)alloc((size_t)NT * (NBK + 1) * 4);
  int* btotals = (int*)alloc((size_t)NBK * 4);
  int* boff = (int*)alloc((size_t)(NBK + 1) * 4);
  int* offsets = (int*)alloc((size_t)(M + 1) * 4);
  unsigned* rec4s = (unsigned*)alloc((size_t)E * 4);

  hipMemsetAsync(btotals, 0, (size_t)NBK * 4, stream);
  prep_theta_k<<<(FIN * FOUT) / 256, 256, 0, stream>>>(theta, thetaT);
  gemm_k<<<(M + 127) / 128, 256, 0, stream>>>(x, thetaT, yb, M);
  tilesort_k<<<NT, 256, 0, stream>>>(rows, cols, vals, rec4tile, rlotile, lofs, btotals, E);
  bscan_k<<<1, 1024, 0, stream>>>(btotals, boff, offsets, E, M);
  bsort_k<<<NBK, 256, 0, stream>>>(boff, lofs, rec4tile, rlotile, rec4s, offsets, NT, M);
  rowv2_k<<<(M * 16 + 255) / 256, 256, 0, stream>>>(offsets, rec4s, yb, bias, out, M);
}

// Round 19
// 292.692 us; speedup vs baseline: 1.7078x; 1.0236x over previous
//
#include <hip/hip_runtime.h>
#include <stdint.h>
#include <stddef.h>

#define FIN 512
#define FOUT 128
#define BROWS 160      // rows per bucket -> NB = 625
#define NBK 625
#define SORT_CAP 7680  // LDS-staged records per bucket (mean 5120, sigma ~72)
#define TILE 8192      // edges per tilesort block

typedef __attribute__((ext_vector_type(8))) short short8;
typedef __attribute__((ext_vector_type(4))) float f32x4;

__device__ __forceinline__ unsigned short f2bf(float f) {
  unsigned u = __builtin_bit_cast(unsigned, f);
  u = (u + 0x7fffu + ((u >> 16) & 1u)) >> 16;
  return (unsigned short)u;
}
__device__ __forceinline__ float bf2f(unsigned short h) {
  unsigned u = ((unsigned)h) << 16;
  return __builtin_bit_cast(float, u);
}

// theta [512][128] f32 -> thetaT [128][512] bf16
__global__ void prep_theta_k(const float* __restrict__ theta,
                             unsigned short* __restrict__ thetaT) {
  int idx = blockIdx.x * blockDim.x + threadIdx.x;  // 65536
  int n = idx >> 9;
  int k = idx & 511;
  thetaT[idx] = f2bf(theta[k * FOUT + n]);
}

// yb[M][128] bf16 = x[M][512] f32 @ thetaT^T, 16x16x32 MFMA, 128x128 tile.
__global__ __launch_bounds__(256) void gemm_k(const float* __restrict__ x,
                                              const unsigned short* __restrict__ thetaT,
                                              unsigned short* __restrict__ yb, int M) {
  __shared__ __align__(16) unsigned short lA[128 * 40];
  __shared__ __align__(16) unsigned short lB[128 * 40];
  const int tid = threadIdx.x;
  const int row0 = blockIdx.x * 128;
  const int wave = tid >> 6, lane = tid & 63;
  const int wm = wave >> 1, wn = wave & 1;
  const int fr = lane & 15, fq = lane >> 4;
  const int arow = tid >> 1, ahalf = tid & 1;

  f32x4 acc[4][4] = {};

  const int grow = row0 + arow;
  const bool aval = (grow < M);
  const float* asrc = x + (size_t)(aval ? grow : 0) * FIN + ahalf * 16;
  const unsigned short* bsrc = thetaT + (size_t)arow * FIN + ahalf * 16;

  for (int k0 = 0; k0 < FIN; k0 += 32) {
    float av[16];
    if (aval) {
      const float4* p = (const float4*)(asrc + k0);
      float4 v0 = p[0], v1 = p[1], v2 = p[2], v3 = p[3];
      av[0] = v0.x; av[1] = v0.y; av[2] = v0.z; av[3] = v0.w;
      av[4] = v1.x; av[5] = v1.y; av[6] = v1.z; av[7] = v1.w;
      av[8] = v2.x; av[9] = v2.y; av[10] = v2.z; av[11] = v2.w;
      av[12] = v3.x; av[13] = v3.y; av[14] = v3.z; av[15] = v3.w;
    } else {
      for (int i = 0; i < 16; i++) av[i] = 0.f;
    }
    unsigned ap[8];
    for (int i = 0; i < 8; i++)
      ap[i] = (unsigned)f2bf(av[2 * i]) | ((unsigned)f2bf(av[2 * i + 1]) << 16);
    uint4* aw = (uint4*)&lA[arow * 40 + ahalf * 16];
    aw[0] = make_uint4(ap[0], ap[1], ap[2], ap[3]);
    aw[1] = make_uint4(ap[4], ap[5], ap[6], ap[7]);

    const uint4* bp = (const uint4*)(bsrc + k0);
    uint4 b0 = bp[0], b1 = bp[1];
    uint4* bw = (uint4*)&lB[arow * 40 + ahalf * 16];
    bw[0] = b0; bw[1] = b1;

    __syncthreads();

    short8 af[4], bfv[4];
#pragma unroll
    for (int m = 0; m < 4; m++)
      af[m] = *(const short8*)&lA[(wm * 64 + m * 16 + fr) * 40 + fq * 8];
#pragma unroll
    for (int n = 0; n < 4; n++)
      bfv[n] = *(const short8*)&lB[(wn * 64 + n * 16 + fr) * 40 + fq * 8];
#pragma unroll
    for (int m = 0; m < 4; m++)
#pragma unroll
      for (int n = 0; n < 4; n++)
        acc[m][n] = __builtin_amdgcn_mfma_f32_16x16x32_bf16(af[m], bfv[n], acc[m][n], 0, 0, 0);

    __syncthreads();
  }

  // C/D layout: col = lane&15, row = (lane>>4)*4 + reg
#pragma unroll
  for (int m = 0; m < 4; m++) {
    int rbase = row0 + wm * 64 + m * 16 + fq * 4;
#pragma unroll
    for (int j = 0; j < 4; j++) {
      int r = rbase + j;
      if (r < M) {
        unsigned short* dst = yb + (size_t)r * FOUT + wn * 64;
#pragma unroll
        for (int n = 0; n < 4; n++) dst[n * 16 + fr] = f2bf(acc[m][n][j]);
      }
    }
  }
}

// tilesort: per 8192-edge tile, LDS count-sort by bucket, dump contiguous.
__global__ __launch_bounds__(256) void tilesort_k(const int* __restrict__ rows,
                                                  const int* __restrict__ cols,
                                                  const float* __restrict__ vals,
                                                  unsigned* __restrict__ rec4tile,
                                                  unsigned char* __restrict__ rlotile,
                                                  int* __restrict__ lofs, int E) {
  __shared__ int hist[NBK];
  __shared__ int wsum[4];
  __shared__ unsigned srec[TILE];
  __shared__ unsigned char srlo[TILE];
  const int c = blockIdx.x, t = threadIdx.x;
  const int base = c * TILE;
  const int n = (E - base < TILE) ? (E - base) : TILE;

  for (int i = t; i < NBK; i += 256) hist[i] = 0;
  __syncthreads();

#pragma unroll
  for (int k = 0; k < TILE / 256; k++) {
    int i = base + k * 256 + t;
    if (i < E) atomicAdd(&hist[rows[i] / BROWS], 1);
  }
  __syncthreads();

  // exclusive scan of hist[0..NBK-1]; 3 entries/thread (768 >= 626)
  int c0 = t * 3, c1 = c0 + 1, c2 = c0 + 2;
  int h0 = (c0 < NBK) ? hist[c0] : 0;
  int h1 = (c1 < NBK) ? hist[c1] : 0;
  int h2 = (c2 < NBK) ? hist[c2] : 0;
  int loc = h0 + h1 + h2;
  int lane = t & 63, wv = t >> 6;
  int inc = loc;
  for (int off = 1; off < 64; off <<= 1) {
    int u = __shfl_up(inc, off, 64);
    if (lane >= off) inc += u;
  }
  if (lane == 63) wsum[wv] = inc;
  __syncthreads();
  int excl = inc - loc;
  for (int i = 0; i < 4; i++)
    if (i < wv) excl += wsum[i];

  size_t lbase = (size_t)c * (NBK + 1);
  int e = excl;
  if (c0 <= NBK) lofs[lbase + c0] = e;
  __syncthreads();  // hist reads done everywhere before cursor overwrite
  if (c0 < NBK) hist[c0] = e;
  e += h0;
  if (c1 <= NBK) lofs[lbase + c1] = e;
  if (c1 < NBK) hist[c1] = e;
  e += h1;
  if (c2 <= NBK) lofs[lbase + c2] = e;
  if (c2 < NBK) hist[c2] = e;
  __syncthreads();

#pragma unroll
  for (int k = 0; k < TILE / 256; k++) {
    int i = base + k * 256 + t;
    if (i < E) {
      int r = rows[i];
      int b = r / BROWS;
      int p = atomicAdd(&hist[b], 1);
      srec[p] = ((unsigned)cols[i] << 15) | ((unsigned)f2bf(vals[i]) & 0x7fffu);
      srlo[p] = (unsigned char)(r - b * BROWS);
    }
  }
  __syncthreads();

  for (int j = t; j < n; j += 256) {
    rec4tile[base + j] = srec[j];
    rlotile[base + j] = srlo[j];
  }
}

// per-bucket totals: 625 blocks, threads parallel over NT fragments
__global__ __launch_bounds__(256) void bsum_k(const int* __restrict__ lofs,
                                              int* __restrict__ btotals, int NT) {
  __shared__ int ws[4];
  int b = blockIdx.x, t = threadIdx.x;
  int s = 0;
  for (int c = t; c < NT; c += 256) {
    size_t lb = (size_t)c * (NBK + 1) + b;
    s += lofs[lb + 1] - lofs[lb];
  }
  for (int off = 32; off; off >>= 1) s += __shfl_down(s, off, 64);
  if ((t & 63) == 0) ws[t >> 6] = s;
  __syncthreads();
  if (t == 0) btotals[b] = ws[0] + ws[1] + ws[2] + ws[3];
}

// single-block exclusive scan of 625 bucket totals -> boff; sentinels
__global__ __launch_bounds__(1024) void bscan_k(const int* __restrict__ btotals,
                                                int* __restrict__ boff,
                                                int* __restrict__ offsets,
                                                int E, int M) {
  __shared__ int tmp[1024];
  int t = threadIdx.x;
  tmp[t] = (t < NBK) ? btotals[t] : 0;
  __syncthreads();
  for (int off = 1; off < 1024; off <<= 1) {
    int v = (t >= off) ? tmp[t - off] : 0;
    __syncthreads();
    tmp[t] += v;
    __syncthreads();
  }
  if (t < NBK) boff[t] = t ? tmp[t - 1] : 0;
  if (t == 0) {
    boff[NBK] = E;
    offsets[M] = E;
  }
}

// per-bucket: gather fragments, LDS count-sort by rlo, write sorted bucket.
__global__ __launch_bounds__(256) void bsort_k(const int* __restrict__ boff,
                                               const int* __restrict__ lofs,
                                               const unsigned* __restrict__ rec4tile,
                                               const unsigned char* __restrict__ rlotile,
                                               unsigned* __restrict__ rec4s,
                                               int* __restrict__ offsets,
                                               int NT, int M) {
  __shared__ unsigned s4[SORT_CAP];
  __shared__ unsigned char k8[SORT_CAP];
  __shared__ int lh[256];
  __shared__ int lsc[256];
  __shared__ int wsum[4];
  int b = blockIdx.x, t = threadIdx.x;
  int start = boff[b];

  int ca = 2 * t, cb = 2 * t + 1;
  int la = 0, fa = 0, lb2 = 0, fb = 0;
  if (ca < NT) {
    size_t p = (size_t)ca * (NBK + 1) + b;
    la = lofs[p];
    fa = lofs[p + 1] - la;
  }
  if (cb < NT) {
    size_t p = (size_t)cb * (NBK + 1) + b;
    lb2 = lofs[p];
    fb = lofs[p + 1] - lb2;
  }
  int loc = fa + fb;
  int lane = t & 63, wv = t >> 6;
  int inc = loc;
  for (int off = 1; off < 64; off <<= 1) {
    int u = __shfl_up(inc, off, 64);
    if (lane >= off) inc += u;
  }
  if (lane == 63) wsum[wv] = inc;
  __syncthreads();
  int excl = inc - loc;
  for (int i = 0; i < 4; i++)
    if (i < wv) excl += wsum[i];

  if (ca < NT) {
    const unsigned* src = rec4tile + (size_t)ca * TILE + la;
    const unsigned char* srl = rlotile + (size_t)ca * TILE + la;
    for (int j = 0; j < fa; j++) {
      int d = excl + j;
      if (d < SORT_CAP) { s4[d] = src[j]; k8[d] = srl[j]; }
    }
    excl += fa;
  }
  if (cb < NT) {
    const unsigned* src = rec4tile + (size_t)cb * TILE + lb2;
    const unsigned char* srl = rlotile + (size_t)cb * TILE + lb2;
    for (int j = 0; j < fb; j++) {
      int d = excl + j;
      if (d < SORT_CAP) { s4[d] = src[j]; k8[d] = srl[j]; }
    }
  }

  int n = boff[b + 1] - start;
  if (n > SORT_CAP) n = SORT_CAP;  // statistically impossible (>35 sigma)
  lh[t] = 0;
  __syncthreads();

  for (int i = t; i < n; i += 256) atomicAdd(&lh[k8[i]], 1);
  __syncthreads();
  lsc[t] = lh[t];
  __syncthreads();
  for (int off = 1; off < 256; off <<= 1) {
    int v = (t >= off) ? lsc[t - off] : 0;
    __syncthreads();
    lsc[t] += v;
    __syncthreads();
  }
  int ex = t ? lsc[t - 1] : 0;
  int row = b * BROWS + t;
  if (t < BROWS && row < M) offsets[row] = start + ex;
  lh[t] = ex;  // reuse as cursor
  __syncthreads();
  for (int i = t; i < n; i += 256) {
    unsigned r = s4[i];
    int p = atomicAdd(&lh[k8[i]], 1);
    rec4s[start + p] = r;
  }
}

// row phase: 16 lanes per row (lane covers 8 feats = one uint4 load / edge),
// edge loop unrolled x2 with independent accumulator sets. Fused bias+relu.
__global__ __launch_bounds__(256) void rowv2_k(const int* __restrict__ offsets,
                                               const unsigned* __restrict__ rec4,
                                               const unsigned short* __restrict__ yb,
                                               const float* __restrict__ bias,
                                               float* __restrict__ out, int M) {
  int gid = blockIdx.x * blockDim.x + threadIdx.x;
  int r = gid >> 4;  // 16 lanes/row
  int l = gid & 15;  // feats [l*8, l*8+8)
  if (r >= M) return;
  int s = offsets[r], e = offsets[r + 1];
  const unsigned short* src = yb + l * 8;

  float a0 = 0.f, a1 = 0.f, a2 = 0.f, a3 = 0.f, a4 = 0.f, a5 = 0.f, a6 = 0.f, a7 = 0.f;
  float c0 = 0.f, c1 = 0.f, c2 = 0.f, c3 = 0.f, c4 = 0.f, c5 = 0.f, c6 = 0.f, c7 = 0.f;

  int i = s;
  for (; i + 2 <= e; i += 2) {
    unsigned q0 = rec4[i];
    unsigned q1 = rec4[i + 1];
    const uint4 u0 = *(const uint4*)(src + (size_t)(q0 >> 15) * FOUT);
    const uint4 u1 = *(const uint4*)(src + (size_t)(q1 >> 15) * FOUT);
    float v0 = __builtin_bit_cast(float, (q0 & 0x7fffu) << 16);
    float v1 = __builtin_bit_cast(float, (q1 & 0x7fffu) << 16);
    a0 += v0 * __builtin_bit_cast(float, u0.x << 16);
    a1 += v0 * __builtin_bit_cast(float, u0.x & 0xffff0000u);
    a2 += v0 * __builtin_bit_cast(float, u0.y << 16);
    a3 += v0 * __builtin_bit_cast(float, u0.y & 0xffff0000u);
    a4 += v0 * __builtin_bit_cast(float, u0.z << 16);
    a5 += v0 * __builtin_bit_cast(float, u0.z & 0xffff0000u);
    a6 += v0 * __builtin_bit_cast(float, u0.w << 16);
    a7 += v0 * __builtin_bit_cast(float, u0.w & 0xffff0000u);
    c0 += v1 * __builtin_bit_cast(float, u1.x << 16);
    c1 += v1 * __builtin_bit_cast(float, u1.x & 0xffff0000u);
    c2 += v1 * __builtin_bit_cast(float, u1.y << 16);
    c3 += v1 * __builtin_bit_cast(float, u1.y & 0xffff0000u);
    c4 += v1 * __builtin_bit_cast(float, u1.z << 16);
    c5 += v1 * __builtin_bit_cast(float, u1.z & 0xffff0000u);
    c6 += v1 * __builtin_bit_cast(float, u1.w << 16);
    c7 += v1 * __builtin_bit_cast(float, u1.w & 0xffff0000u);
  }
  if (i < e) {
    unsigned q0 = rec4[i];
    const uint4 u0 = *(const uint4*)(src + (size_t)(q0 >> 15) * FOUT);
    float v0 = __builtin_bit_cast(float, (q0 & 0x7fffu) << 16);
    a0 += v0 * __builtin_bit_cast(float, u0.x << 16);
    a1 += v0 * __builtin_bit_cast(float, u0.x & 0xffff0000u);
    a2 += v0 * __builtin_bit_cast(float, u0.y << 16);
    a3 += v0 * __builtin_bit_cast(float, u0.y & 0xffff0000u);
    a4 += v0 * __builtin_bit_cast(float, u0.z << 16);
    a5 += v0 * __builtin_bit_cast(float, u0.z & 0xffff0000u);
    a6 += v0 * __builtin_bit_cast(float, u0.w << 16);
    a7 += v0 * __builtin_bit_cast(float, u0.w & 0xffff0000u);
  }

  const float4 b0 = *(const float4*)(bias + l * 8);
  const float4 b1 = *(const float4*)(bias + l * 8 + 4);
  float* dst = out + (size_t)r * FOUT + l * 8;
  float4 o0, o1;
  o0.x = fmaxf(a0 + c0 + b0.x, 0.f);
  o0.y = fmaxf(a1 + c1 + b0.y, 0.f);
  o0.z = fmaxf(a2 + c2 + b0.z, 0.f);
  o0.w = fmaxf(a3 + c3 + b0.w, 0.f);
  o1.x = fmaxf(a4 + c4 + b1.x, 0.f);
  o1.y = fmaxf(a5 + c5 + b1.y, 0.f);
  o1.z = fmaxf(a6 + c6 + b1.z, 0.f);
  o1.w = fmaxf(a7 + c7 + b1.w, 0.f);
  *(float4*)(dst) = o0;
  *(float4*)(dst + 4) = o1;
}

extern "C" void kernel_launch(void* const* d_in, const int* in_sizes, int n_in,
                              void* d_out, int out_size, void* d_ws, size_t ws_size,
                              hipStream_t stream) {
  const float* x = (const float*)d_in[0];
  const int* rows = (const int*)d_in[1];
  const int* cols = (const int*)d_in[2];
  const float* vals = (const float*)d_in[3];
  const float* theta = (const float*)d_in[4];
  const float* bias = (const float*)d_in[5];
  float* out = (float*)d_out;
  const int M = in_sizes[0] / FIN;       // 100000
  const int E = in_sizes[1];             // 3200000
  const int NT = (E + TILE - 1) / TILE;  // 391 tiles

  char* w = (char*)d_ws;
  auto alloc = [&](size_t bytes) {
    char* p = w;
    w += (bytes + 255) & ~(size_t)255;
    return p;
  };
  unsigned short* yb = (unsigned short*)alloc((size_t)M * FOUT * 2);
  unsigned short* thetaT = (unsigned short*)alloc((size_t)FIN * FOUT * 2);
  unsigned* rec4tile = (unsigned*)alloc((size_t)NT * TILE * 4);
  unsigned char* rlotile = (unsigned char*)alloc((size_t)NT * TILE);
  int* lofs = (int*)alloc((size_t)NT * (NBK + 1) * 4);
  int* btotals = (int*)alloc((size_t)NBK * 4);
  int* boff = (int*)alloc((size_t)(NBK + 1) * 4);
  int* offsets = (int*)alloc((size_t)(M + 1) * 4);
  unsigned* rec4s = (unsigned*)alloc((size_t)E * 4);

  prep_theta_k<<<(FIN * FOUT) / 256, 256, 0, stream>>>(theta, thetaT);
  gemm_k<<<(M + 127) / 128, 256, 0, stream>>>(x, thetaT, yb, M);
  tilesort_k<<<NT, 256, 0, stream>>>(rows, cols, vals, rec4tile, rlotile, lofs, E);
  bsum_k<<<NBK, 256, 0, stream>>>(lofs, btotals, NT);
  bscan_k<<<1, 1024, 0, stream>>>(btotals, boff, offsets, E, M);
  bsort_k<<<NBK, 256, 0, stream>>>(boff, lofs, rec4tile, rlotile, rec4s, offsets, NT, M);
  rowv2_k<<<(M * 16 + 255) / 256, 256, 0, stream>>>(offsets, rec4s, yb, bias, out, M);
}